// Round 6
// baseline (175.837 us; speedup 1.0000x reference)
//
#include <hip/hip_runtime.h>
#include <math.h>

#define TT 60
#define BB 64
#define STR 68
#define NBINS 45

// ---------------- Phase 1: contiguous streaming partial sums ----------------
// 512 blocks x 512 threads. Block = quarter of one (tensor,b): 15 timesteps =
// 30720 float4, read fully CONTIGUOUSLY (m13 copy-kernel access shape).
// Iteration k covers one 8KB block-contiguous chunk = half a channel-image.
// Slot map (k mod 4): k%4=0 ->(c0,half0), 1 ->(c0,half1), 2 ->(c1,half0), 3 ->(c1,half1).
// Cross-slab (4 blocks per (tensor,b)) reduction via global atomicAdd staging.
#define ACC1(S, Q, V) do {                                       \
    S.x += V.x; Q.x += V.x * V.x;                                \
    S.y += V.y; Q.y += V.y * V.y;                                \
    S.z += V.z; Q.z += V.z * V.z;                                \
    S.w += V.w; Q.w += V.w * V.w;                                \
} while (0)

__global__ __launch_bounds__(512, 4) void tke_partial(const float* __restrict__ preds,
                                                      const float* __restrict__ trues,
                                                      float* __restrict__ stage) {
    int tid     = threadIdx.x;
    int slab    = blockIdx.x;
    int tensor  = slab >> 8;
    int b       = (slab >> 2) & 63;
    int quarter = slab & 3;

    const float4* base = (const float4*)(tensor ? trues : preds)
                         + (size_t)b * 122880 + (size_t)quarter * 30720 + tid;

    float4 s0 = {0,0,0,0}, s1 = {0,0,0,0}, s2 = {0,0,0,0}, s3 = {0,0,0,0};
    float4 q0 = {0,0,0,0}, q1 = {0,0,0,0}, q2 = {0,0,0,0}, q3 = {0,0,0,0};

    for (int k = 0; k < 60; k += 4) {
        float4 va = base[(k + 0) * 512];
        float4 vb = base[(k + 1) * 512];
        float4 vc = base[(k + 2) * 512];
        float4 vd = base[(k + 3) * 512];
        ACC1(s0, q0, va);
        ACC1(s1, q1, vb);
        ACC1(s2, q2, vc);
        ACC1(s3, q3, vd);
    }

    // stage layout (floats): [(tensor*64+b)][c][stat][1024 float4 * 4]
    // f-index = (((ib*2+c)*2+stat)*1024 + half*512 + tid) * 4 + comp
    size_t ib = (size_t)(tensor * BB + b);
#define ATOM(S, Q, C, H) do {                                                         \
    size_t fb = ((((ib * 2 + (C)) * 2 + 0) * 1024) + (size_t)(H) * 512 + tid) * 4;    \
    size_t fq = fb + 4096;                                                            \
    atomicAdd(&stage[fb + 0], S.x); atomicAdd(&stage[fb + 1], S.y);                   \
    atomicAdd(&stage[fb + 2], S.z); atomicAdd(&stage[fb + 3], S.w);                   \
    atomicAdd(&stage[fq + 0], Q.x); atomicAdd(&stage[fq + 1], Q.y);                   \
    atomicAdd(&stage[fq + 2], Q.z); atomicAdd(&stage[fq + 3], Q.w);                   \
} while (0)
    ATOM(s0, q0, 0, 0);
    ATOM(s1, q1, 0, 1);
    ATOM(s2, q2, 1, 0);
    ATOM(s3, q3, 1, 1);
#undef ATOM
}

// ---------------- Phase 1b: finalize variance -> TKE image ----------------
__global__ __launch_bounds__(256) void tke_final(const float* __restrict__ stage,
                                                 float* __restrict__ tke) {
    int gid    = blockIdx.x * 256 + threadIdx.x;   // 131072 = 2*64*1024
    int tensor = gid >> 16;
    int b      = (gid >> 10) & 63;
    int p4     = gid & 1023;
    size_t ib  = (size_t)(tensor * BB + b);

    const float4* st = (const float4*)stage;
    float4 su0 = st[((ib * 2 + 0) * 2 + 0) * 1024 + p4];
    float4 sq0 = st[((ib * 2 + 0) * 2 + 1) * 1024 + p4];
    float4 su1 = st[((ib * 2 + 1) * 2 + 0) * 1024 + p4];
    float4 sq1 = st[((ib * 2 + 1) * 2 + 1) * 1024 + p4];

    const float inv = 1.0f / 60.0f;
    float4 o;
    {
        float mu0 = su0.x * inv, mu1 = su1.x * inv;
        o.x = 0.5f * ((sq0.x * inv - mu0 * mu0) + (sq1.x * inv - mu1 * mu1));
        mu0 = su0.y * inv; mu1 = su1.y * inv;
        o.y = 0.5f * ((sq0.y * inv - mu0 * mu0) + (sq1.y * inv - mu1 * mu1));
        mu0 = su0.z * inv; mu1 = su1.z * inv;
        o.z = 0.5f * ((sq0.z * inv - mu0 * mu0) + (sq1.z * inv - mu1 * mu1));
        mu0 = su0.w * inv; mu1 = su1.w * inv;
        o.w = 0.5f * ((sq0.w * inv - mu0 * mu0) + (sq1.w * inv - mu1 * mu1));
    }
    ((float4*)tke)[ib * 1024 + p4] = o;
}

// ---------------- Kernel 2: 2D DFT + power + radial bin sums ----------------
// one block (512 threads) per image; 128 images (64 preds then 64 trues)
__global__ __launch_bounds__(512) void dft_kernel(const float* __restrict__ tke,
                                                  float* __restrict__ binsums) {
    __shared__ __align__(16) float tke_s[64 * 64];
    __shared__ __align__(16) float Gr[64 * STR];   // stored [x][k], stride 68
    __shared__ __align__(16) float Gi[64 * STR];
    __shared__ float ctab[64], stab[64];
    __shared__ float bins_s[NBINS];

    int tid = threadIdx.x;
    int img = blockIdx.x;

    if (tid < 64) {
        float ang = (float)tid * 0.09817477042468103871f;   // 2*pi/64
        float ss, cc;
        sincosf(ang, &ss, &cc);
        ctab[tid] = cc; stab[tid] = ss;
    }
    if (tid < NBINS) bins_s[tid] = 0.0f;

    // load TKE image to LDS
    {
        const float4* src = (const float4*)(tke + (size_t)img * 4096);
        float4* dst = (float4*)tke_s;
        for (int i = tid; i < 1024; i += 512) dst[i] = src[i];
    }
    __syncthreads();

    // Stage A: G[k][x] = sum_y tke[y][x] * exp(-2pi i k y / 64)
    // thread owns k = tid>>3 (0..63), x-range x0..x0+7
    {
        int k  = tid >> 3;
        int x0 = (tid & 7) * 8;
        float gr[8] = {0,0,0,0,0,0,0,0};
        float gi[8] = {0,0,0,0,0,0,0,0};
        for (int y = 0; y < 64; ++y) {
            float4 ta = *(const float4*)&tke_s[(y << 6) + x0];
            float4 tb = *(const float4*)&tke_s[(y << 6) + x0 + 4];
            float tv[8] = {ta.x, ta.y, ta.z, ta.w, tb.x, tb.y, tb.z, tb.w};
            int idx = (k * y) & 63;
            float cc = ctab[idx], ss = stab[idx];
            #pragma unroll
            for (int j = 0; j < 8; ++j) {
                gr[j] += cc * tv[j];
                gi[j] -= ss * tv[j];
            }
        }
        #pragma unroll
        for (int j = 0; j < 8; ++j) {           // transposed store: G[x][k]
            Gr[(x0 + j) * STR + k] = gr[j];
            Gi[(x0 + j) * STR + k] = gi[j];
        }
    }
    __syncthreads();

    // Stage B: F[k][l] = sum_x G[k][x] * exp(-2pi i l x / 64); power + binning
    // thread owns l = tid>>3 (0..63), k-range k0..k0+7
    {
        int l  = tid >> 3;
        int k0 = (tid & 7) * 8;
        float fr[8] = {0,0,0,0,0,0,0,0};
        float fi[8] = {0,0,0,0,0,0,0,0};
        for (int x = 0; x < 64; ++x) {
            float4 a0 = *(const float4*)&Gr[x * STR + k0];
            float4 a1 = *(const float4*)&Gr[x * STR + k0 + 4];
            float4 b0 = *(const float4*)&Gi[x * STR + k0];
            float4 b1 = *(const float4*)&Gi[x * STR + k0 + 4];
            float ar[8] = {a0.x, a0.y, a0.z, a0.w, a1.x, a1.y, a1.z, a1.w};
            float br[8] = {b0.x, b0.y, b0.z, b0.w, b1.x, b1.y, b1.z, b1.w};
            int idx = (l * x) & 63;
            float cc = ctab[idx], ss = stab[idx];
            #pragma unroll
            for (int j = 0; j < 8; ++j) {
                fr[j] += ar[j] * cc + br[j] * ss;
                fi[j] += br[j] * cc - ar[j] * ss;
            }
        }
        float fl = (float)((l + 32) & 63) - 31.5f;
        #pragma unroll
        for (int j = 0; j < 8; ++j) {
            int k = k0 + j;
            float fk = (float)((k + 32) & 63) - 31.5f;
            float r = sqrtf(fk * fk + fl * fl);
            int bin = (int)r;
            float pw = fr[j] * fr[j] + fi[j] * fi[j];
            atomicAdd(&bins_s[bin], pw);
        }
    }
    __syncthreads();
    if (tid < NBINS) binsums[img * NBINS + tid] = bins_s[tid];
}

// ---------------- Kernel 3: MSE over azimuthal spectra ----------------
__global__ __launch_bounds__(256) void loss_kernel(const float* __restrict__ binsums,
                                                   float* __restrict__ out) {
    __shared__ int   cnt[NBINS];
    __shared__ float part[256];
    int tid = threadIdx.x;
    if (tid < NBINS) cnt[tid] = 0;
    __syncthreads();
    for (int p = tid; p < 4096; p += 256) {
        float dy = (float)(p >> 6) - 31.5f;
        float dx = (float)(p & 63) - 31.5f;
        int bin = (int)sqrtf(dy * dy + dx * dx);
        atomicAdd(&cnt[bin], 1);
    }
    __syncthreads();
    float acc = 0.0f;
    for (int j = tid; j < BB * 43; j += 256) {
        int b   = j / 43;
        int bin = j - b * 43 + 1;           // returned bins are 1..43
        float n  = (float)cnt[bin];
        float st = binsums[(BB + b) * NBINS + bin] / n;   // trues
        float sp = binsums[b * NBINS + bin] / n;          // preds
        float d  = st - sp;
        acc += d * d;
    }
    part[tid] = acc;
    __syncthreads();
    for (int s = 128; s > 0; s >>= 1) {
        if (tid < s) part[tid] += part[tid + s];
        __syncthreads();
    }
    if (tid == 0) out[0] = part[0] * (1.0f / (BB * 43.0f));
}

extern "C" void kernel_launch(void* const* d_in, const int* in_sizes, int n_in,
                              void* d_out, int out_size, void* d_ws, size_t ws_size,
                              hipStream_t stream) {
    const float* preds = (const float*)d_in[0];
    const float* trues = (const float*)d_in[1];

    float* stage   = (float*)d_ws;                  // 2*64*2*2*4096 floats = 8 MB
    float* tke     = stage + 2097152;               // 2*64*4096 floats   = 2 MB
    float* binsums = tke + 524288;                  // 128*45 floats

    hipMemsetAsync(stage, 0, 2097152 * sizeof(float), stream);
    tke_partial<<<512, 512, 0, stream>>>(preds, trues, stage);
    tke_final<<<512, 256, 0, stream>>>(stage, tke);
    dft_kernel<<<128, 512, 0, stream>>>(tke, binsums);
    loss_kernel<<<1, 256, 0, stream>>>(binsums, (float*)d_out);
}

// Round 7
// 73.102 us; speedup vs baseline: 2.4054x; 2.4054x over previous
//
#include <hip/hip_runtime.h>
#include <math.h>

#define TT 60
#define BB 64
#define STR 68
#define NBINS 45

// ---------------- Kernel 1: TKE (temporal variance) ----------------
// r1 structure (best measured): 512 blocks x 256 threads, thread owns one
// float4-pixel for all 60 t. NEW: 5-timestep batches of 10 independent loads
// separated from their accumulation by sched_barrier(0), which the scheduler
// cannot cross -> all 10 loads issue before any use, ~10 in flight per thread
// (r1-r4 post-mortems: without a hard fence hipcc folds loads into uses and
// keeps only ~2 in flight; inline-asm loads (r5) fault).
__global__ __launch_bounds__(256, 4) void tke_kernel(const float* __restrict__ preds,
                                                     const float* __restrict__ trues,
                                                     float* __restrict__ tke) {
    int gtid  = blockIdx.x * 256 + threadIdx.x;
    int input = gtid >> 16;          // 65536 float4-threads per input
    int rem   = gtid & 65535;
    int b     = rem >> 10;           // batch
    int p4    = rem & 1023;          // float4 index within 64x64 image

    const float4* src  = (const float4*)(input ? trues : preds);
    const float4* base = src + (size_t)b * (TT * 2048) + p4;

    float su[4]  = {0, 0, 0, 0}, squ[4] = {0, 0, 0, 0};
    float sv[4]  = {0, 0, 0, 0}, sqv[4] = {0, 0, 0, 0};

    #pragma unroll
    for (int tb = 0; tb < TT; tb += 5) {
        float4 r[10];
        #pragma unroll
        for (int i = 0; i < 5; ++i) {
            r[2 * i]     = base[(tb + i) * 2048];          // c = 0
            r[2 * i + 1] = base[(tb + i) * 2048 + 1024];   // c = 1
        }
        // Hard scheduling wall: no accumulate may be hoisted above, no load
        // may sink below. Forces all 10 loads in flight simultaneously.
        __builtin_amdgcn_sched_barrier(0);
        #pragma unroll
        for (int i = 0; i < 5; ++i) {
            float4 u = r[2 * i], v = r[2 * i + 1];
            su[0] += u.x; squ[0] += u.x * u.x; sv[0] += v.x; sqv[0] += v.x * v.x;
            su[1] += u.y; squ[1] += u.y * u.y; sv[1] += v.y; sqv[1] += v.y * v.y;
            su[2] += u.z; squ[2] += u.z * u.z; sv[2] += v.z; sqv[2] += v.z * v.z;
            su[3] += u.w; squ[3] += u.w * u.w; sv[3] += v.w; sqv[3] += v.w * v.w;
        }
    }

    const float inv = 1.0f / 60.0f;
    float o[4];
    #pragma unroll
    for (int j = 0; j < 4; ++j) {
        float mu = su[j] * inv, mv = sv[j] * inv;
        o[j] = 0.5f * ((squ[j] * inv - mu * mu) + (sqv[j] * inv - mv * mv));
    }
    float4 outv; outv.x = o[0]; outv.y = o[1]; outv.z = o[2]; outv.w = o[3];
    ((float4*)tke)[(size_t)(input * BB + b) * 1024 + p4] = outv;
}

// ---------------- Kernel 2: 2D DFT + power + radial bin sums ----------------
// one block (512 threads) per image; 128 images (64 preds then 64 trues)
__global__ __launch_bounds__(512) void dft_kernel(const float* __restrict__ tke,
                                                  float* __restrict__ binsums) {
    __shared__ __align__(16) float tke_s[64 * 64];
    __shared__ __align__(16) float Gr[64 * STR];   // stored [x][k], stride 68
    __shared__ __align__(16) float Gi[64 * STR];
    __shared__ float ctab[64], stab[64];
    __shared__ float bins_s[NBINS];

    int tid = threadIdx.x;
    int img = blockIdx.x;

    if (tid < 64) {
        float ang = (float)tid * 0.09817477042468103871f;   // 2*pi/64
        float ss, cc;
        sincosf(ang, &ss, &cc);
        ctab[tid] = cc; stab[tid] = ss;
    }
    if (tid < NBINS) bins_s[tid] = 0.0f;

    // load TKE image to LDS
    {
        const float4* src = (const float4*)(tke + (size_t)img * 4096);
        float4* dst = (float4*)tke_s;
        for (int i = tid; i < 1024; i += 512) dst[i] = src[i];
    }
    __syncthreads();

    // Stage A: G[k][x] = sum_y tke[y][x] * exp(-2pi i k y / 64)
    // thread owns k = tid>>3 (0..63), x-range x0..x0+7
    {
        int k  = tid >> 3;
        int x0 = (tid & 7) * 8;
        float gr[8] = {0,0,0,0,0,0,0,0};
        float gi[8] = {0,0,0,0,0,0,0,0};
        for (int y = 0; y < 64; ++y) {
            float4 ta = *(const float4*)&tke_s[(y << 6) + x0];
            float4 tb = *(const float4*)&tke_s[(y << 6) + x0 + 4];
            float tv[8] = {ta.x, ta.y, ta.z, ta.w, tb.x, tb.y, tb.z, tb.w};
            int idx = (k * y) & 63;
            float cc = ctab[idx], ss = stab[idx];
            #pragma unroll
            for (int j = 0; j < 8; ++j) {
                gr[j] += cc * tv[j];
                gi[j] -= ss * tv[j];
            }
        }
        #pragma unroll
        for (int j = 0; j < 8; ++j) {           // transposed store: G[x][k]
            Gr[(x0 + j) * STR + k] = gr[j];
            Gi[(x0 + j) * STR + k] = gi[j];
        }
    }
    __syncthreads();

    // Stage B: F[k][l] = sum_x G[k][x] * exp(-2pi i l x / 64); power + binning
    // thread owns l = tid>>3 (0..63), k-range k0..k0+7
    {
        int l  = tid >> 3;
        int k0 = (tid & 7) * 8;
        float fr[8] = {0,0,0,0,0,0,0,0};
        float fi[8] = {0,0,0,0,0,0,0,0};
        for (int x = 0; x < 64; ++x) {
            float4 a0 = *(const float4*)&Gr[x * STR + k0];
            float4 a1 = *(const float4*)&Gr[x * STR + k0 + 4];
            float4 b0 = *(const float4*)&Gi[x * STR + k0];
            float4 b1 = *(const float4*)&Gi[x * STR + k0 + 4];
            float ar[8] = {a0.x, a0.y, a0.z, a0.w, a1.x, a1.y, a1.z, a1.w};
            float br[8] = {b0.x, b0.y, b0.z, b0.w, b1.x, b1.y, b1.z, b1.w};
            int idx = (l * x) & 63;
            float cc = ctab[idx], ss = stab[idx];
            #pragma unroll
            for (int j = 0; j < 8; ++j) {
                fr[j] += ar[j] * cc + br[j] * ss;
                fi[j] += br[j] * cc - ar[j] * ss;
            }
        }
        float fl = (float)((l + 32) & 63) - 31.5f;
        #pragma unroll
        for (int j = 0; j < 8; ++j) {
            int k = k0 + j;
            float fk = (float)((k + 32) & 63) - 31.5f;
            float r = sqrtf(fk * fk + fl * fl);
            int bin = (int)r;
            float pw = fr[j] * fr[j] + fi[j] * fi[j];
            atomicAdd(&bins_s[bin], pw);
        }
    }
    __syncthreads();
    if (tid < NBINS) binsums[img * NBINS + tid] = bins_s[tid];
}

// ---------------- Kernel 3: MSE over azimuthal spectra ----------------
__global__ __launch_bounds__(256) void loss_kernel(const float* __restrict__ binsums,
                                                   float* __restrict__ out) {
    __shared__ int   cnt[NBINS];
    __shared__ float part[256];
    int tid = threadIdx.x;
    if (tid < NBINS) cnt[tid] = 0;
    __syncthreads();
    for (int p = tid; p < 4096; p += 256) {
        float dy = (float)(p >> 6) - 31.5f;
        float dx = (float)(p & 63) - 31.5f;
        int bin = (int)sqrtf(dy * dy + dx * dx);
        atomicAdd(&cnt[bin], 1);
    }
    __syncthreads();
    float acc = 0.0f;
    for (int j = tid; j < BB * 43; j += 256) {
        int b   = j / 43;
        int bin = j - b * 43 + 1;           // returned bins are 1..43
        float n  = (float)cnt[bin];
        float st = binsums[(BB + b) * NBINS + bin] / n;   // trues
        float sp = binsums[b * NBINS + bin] / n;          // preds
        float d  = st - sp;
        acc += d * d;
    }
    part[tid] = acc;
    __syncthreads();
    for (int s = 128; s > 0; s >>= 1) {
        if (tid < s) part[tid] += part[tid + s];
        __syncthreads();
    }
    if (tid == 0) out[0] = part[0] * (1.0f / (BB * 43.0f));
}

extern "C" void kernel_launch(void* const* d_in, const int* in_sizes, int n_in,
                              void* d_out, int out_size, void* d_ws, size_t ws_size,
                              hipStream_t stream) {
    const float* preds = (const float*)d_in[0];
    const float* trues = (const float*)d_in[1];
    float* tke     = (float*)d_ws;                  // 2*64*4096 floats = 2 MB
    float* binsums = tke + 2 * BB * 4096;           // 128*45 floats

    tke_kernel<<<512, 256, 0, stream>>>(preds, trues, tke);
    dft_kernel<<<128, 512, 0, stream>>>(tke, binsums);
    loss_kernel<<<1, 256, 0, stream>>>(binsums, (float*)d_out);
}

// Round 8
// 71.723 us; speedup vs baseline: 2.4516x; 1.0192x over previous
//
#include <hip/hip_runtime.h>
#include <math.h>

#define TT 60
#define BB 64
#define STR 68
#define NBINS 45

// ---------------- Kernel 1: TKE (temporal variance) ----------------
// BOTH levers at once (r2 gave occupancy w/o ILP; r7 gave ILP w/o occupancy):
// 2048 blocks x 256 threads; block = 64 float4-pixels x 4 t-chunks of 15.
// Each t-chunk: 3 fenced batches of 10 independent loads (sched_barrier wall
// keeps ~10 in flight, proven r7 via VGPR 36->64). launch_bounds(256,6):
// VGPR cap ~85 -> 24 waves/CU. Cross-chunk reduction: float4 LDS slots, 1 sync.
__global__ __launch_bounds__(256, 6) void tke_kernel(const float* __restrict__ preds,
                                                     const float* __restrict__ trues,
                                                     float* __restrict__ tke) {
    __shared__ float4 red[3][256];   // [tc-1][stat*64 + p]

    int tid = threadIdx.x;
    int p   = tid & 63;     // pixel within block's 64-float4 group
    int tc  = tid >> 6;     // t-chunk 0..3 (15 timesteps each)

    int bid   = blockIdx.x;
    int input = bid >> 10;          // 1024 blocks per input
    int rem   = bid & 1023;
    int b     = rem >> 4;           // batch
    int pg    = rem & 15;           // 16 pixel-groups per image
    int p4    = pg * 64 + p;

    const float4* src  = (const float4*)(input ? trues : preds);
    const float4* base = src + (size_t)b * (TT * 2048) + (size_t)(tc * 15) * 2048 + p4;

    float4 su  = {0, 0, 0, 0}, squ = {0, 0, 0, 0};
    float4 sv  = {0, 0, 0, 0}, sqv = {0, 0, 0, 0};

    #pragma unroll
    for (int tb = 0; tb < 15; tb += 5) {
        float4 r[10];
        #pragma unroll
        for (int i = 0; i < 5; ++i) {
            r[2 * i]     = base[(tb + i) * 2048];          // c = 0
            r[2 * i + 1] = base[(tb + i) * 2048 + 1024];   // c = 1
        }
        // Hard scheduling wall: all 10 loads issue before any accumulate.
        __builtin_amdgcn_sched_barrier(0);
        #pragma unroll
        for (int i = 0; i < 5; ++i) {
            float4 u = r[2 * i], v = r[2 * i + 1];
            su.x += u.x; squ.x += u.x * u.x; sv.x += v.x; sqv.x += v.x * v.x;
            su.y += u.y; squ.y += u.y * u.y; sv.y += v.y; sqv.y += v.y * v.y;
            su.z += u.z; squ.z += u.z * u.z; sv.z += v.z; sqv.z += v.z * v.z;
            su.w += u.w; squ.w += u.w * u.w; sv.w += v.w; sqv.w += v.w * v.w;
        }
    }

    if (tc != 0) {
        red[tc - 1][0 * 64 + p] = su;
        red[tc - 1][1 * 64 + p] = squ;
        red[tc - 1][2 * 64 + p] = sv;
        red[tc - 1][3 * 64 + p] = sqv;
    }
    __syncthreads();

    if (tc == 0) {
        #pragma unroll
        for (int s = 0; s < 3; ++s) {
            float4 a = red[s][0 * 64 + p], c = red[s][1 * 64 + p];
            float4 d = red[s][2 * 64 + p], e = red[s][3 * 64 + p];
            su.x += a.x; su.y += a.y; su.z += a.z; su.w += a.w;
            squ.x += c.x; squ.y += c.y; squ.z += c.z; squ.w += c.w;
            sv.x += d.x; sv.y += d.y; sv.z += d.z; sv.w += d.w;
            sqv.x += e.x; sqv.y += e.y; sqv.z += e.z; sqv.w += e.w;
        }
        const float inv = 1.0f / 60.0f;
        float4 o;
        {
            float mu = su.x * inv, mv = sv.x * inv;
            o.x = 0.5f * ((squ.x * inv - mu * mu) + (sqv.x * inv - mv * mv));
            mu = su.y * inv; mv = sv.y * inv;
            o.y = 0.5f * ((squ.y * inv - mu * mu) + (sqv.y * inv - mv * mv));
            mu = su.z * inv; mv = sv.z * inv;
            o.z = 0.5f * ((squ.z * inv - mu * mu) + (sqv.z * inv - mv * mv));
            mu = su.w * inv; mv = sv.w * inv;
            o.w = 0.5f * ((squ.w * inv - mu * mu) + (sqv.w * inv - mv * mv));
        }
        ((float4*)tke)[(size_t)(input * BB + b) * 1024 + p4] = o;
    }
}

// ---------------- Kernel 2: 2D DFT + power + radial bin sums ----------------
// one block (512 threads) per image; 128 images (64 preds then 64 trues)
__global__ __launch_bounds__(512) void dft_kernel(const float* __restrict__ tke,
                                                  float* __restrict__ binsums) {
    __shared__ __align__(16) float tke_s[64 * 64];
    __shared__ __align__(16) float Gr[64 * STR];   // stored [x][k], stride 68
    __shared__ __align__(16) float Gi[64 * STR];
    __shared__ float ctab[64], stab[64];
    __shared__ float bins_s[NBINS];

    int tid = threadIdx.x;
    int img = blockIdx.x;

    if (tid < 64) {
        float ang = (float)tid * 0.09817477042468103871f;   // 2*pi/64
        float ss, cc;
        sincosf(ang, &ss, &cc);
        ctab[tid] = cc; stab[tid] = ss;
    }
    if (tid < NBINS) bins_s[tid] = 0.0f;

    // load TKE image to LDS
    {
        const float4* src = (const float4*)(tke + (size_t)img * 4096);
        float4* dst = (float4*)tke_s;
        for (int i = tid; i < 1024; i += 512) dst[i] = src[i];
    }
    __syncthreads();

    // Stage A: G[k][x] = sum_y tke[y][x] * exp(-2pi i k y / 64)
    // thread owns k = tid>>3 (0..63), x-range x0..x0+7
    {
        int k  = tid >> 3;
        int x0 = (tid & 7) * 8;
        float gr[8] = {0,0,0,0,0,0,0,0};
        float gi[8] = {0,0,0,0,0,0,0,0};
        for (int y = 0; y < 64; ++y) {
            float4 ta = *(const float4*)&tke_s[(y << 6) + x0];
            float4 tb = *(const float4*)&tke_s[(y << 6) + x0 + 4];
            float tv[8] = {ta.x, ta.y, ta.z, ta.w, tb.x, tb.y, tb.z, tb.w};
            int idx = (k * y) & 63;
            float cc = ctab[idx], ss = stab[idx];
            #pragma unroll
            for (int j = 0; j < 8; ++j) {
                gr[j] += cc * tv[j];
                gi[j] -= ss * tv[j];
            }
        }
        #pragma unroll
        for (int j = 0; j < 8; ++j) {           // transposed store: G[x][k]
            Gr[(x0 + j) * STR + k] = gr[j];
            Gi[(x0 + j) * STR + k] = gi[j];
        }
    }
    __syncthreads();

    // Stage B: F[k][l] = sum_x G[k][x] * exp(-2pi i l x / 64); power + binning
    // thread owns l = tid>>3 (0..63), k-range k0..k0+7
    {
        int l  = tid >> 3;
        int k0 = (tid & 7) * 8;
        float fr[8] = {0,0,0,0,0,0,0,0};
        float fi[8] = {0,0,0,0,0,0,0,0};
        for (int x = 0; x < 64; ++x) {
            float4 a0 = *(const float4*)&Gr[x * STR + k0];
            float4 a1 = *(const float4*)&Gr[x * STR + k0 + 4];
            float4 b0 = *(const float4*)&Gi[x * STR + k0];
            float4 b1 = *(const float4*)&Gi[x * STR + k0 + 4];
            float ar[8] = {a0.x, a0.y, a0.z, a0.w, a1.x, a1.y, a1.z, a1.w};
            float br[8] = {b0.x, b0.y, b0.z, b0.w, b1.x, b1.y, b1.z, b1.w};
            int idx = (l * x) & 63;
            float cc = ctab[idx], ss = stab[idx];
            #pragma unroll
            for (int j = 0; j < 8; ++j) {
                fr[j] += ar[j] * cc + br[j] * ss;
                fi[j] += br[j] * cc - ar[j] * ss;
            }
        }
        float fl = (float)((l + 32) & 63) - 31.5f;
        #pragma unroll
        for (int j = 0; j < 8; ++j) {
            int k = k0 + j;
            float fk = (float)((k + 32) & 63) - 31.5f;
            float r = sqrtf(fk * fk + fl * fl);
            int bin = (int)r;
            float pw = fr[j] * fr[j] + fi[j] * fi[j];
            atomicAdd(&bins_s[bin], pw);
        }
    }
    __syncthreads();
    if (tid < NBINS) binsums[img * NBINS + tid] = bins_s[tid];
}

// ---------------- Kernel 3: MSE over azimuthal spectra ----------------
__global__ __launch_bounds__(256) void loss_kernel(const float* __restrict__ binsums,
                                                   float* __restrict__ out) {
    __shared__ int   cnt[NBINS];
    __shared__ float part[256];
    int tid = threadIdx.x;
    if (tid < NBINS) cnt[tid] = 0;
    __syncthreads();
    for (int p = tid; p < 4096; p += 256) {
        float dy = (float)(p >> 6) - 31.5f;
        float dx = (float)(p & 63) - 31.5f;
        int bin = (int)sqrtf(dy * dy + dx * dx);
        atomicAdd(&cnt[bin], 1);
    }
    __syncthreads();
    float acc = 0.0f;
    for (int j = tid; j < BB * 43; j += 256) {
        int b   = j / 43;
        int bin = j - b * 43 + 1;           // returned bins are 1..43
        float n  = (float)cnt[bin];
        float st = binsums[(BB + b) * NBINS + bin] / n;   // trues
        float sp = binsums[b * NBINS + bin] / n;          // preds
        float d  = st - sp;
        acc += d * d;
    }
    part[tid] = acc;
    __syncthreads();
    for (int s = 128; s > 0; s >>= 1) {
        if (tid < s) part[tid] += part[tid + s];
        __syncthreads();
    }
    if (tid == 0) out[0] = part[0] * (1.0f / (BB * 43.0f));
}

extern "C" void kernel_launch(void* const* d_in, const int* in_sizes, int n_in,
                              void* d_out, int out_size, void* d_ws, size_t ws_size,
                              hipStream_t stream) {
    const float* preds = (const float*)d_in[0];
    const float* trues = (const float*)d_in[1];
    float* tke     = (float*)d_ws;                  // 2*64*4096 floats = 2 MB
    float* binsums = tke + 2 * BB * 4096;           // 128*45 floats

    tke_kernel<<<2048, 256, 0, stream>>>(preds, trues, tke);
    dft_kernel<<<128, 512, 0, stream>>>(tke, binsums);
    loss_kernel<<<1, 256, 0, stream>>>(binsums, (float*)d_out);
}